// Round 12
// baseline (195.371 us; speedup 1.0000x reference)
//
#include <hip/hip_runtime.h>
#include <stdint.h>

#define Mdim 4096
#define Kdim 4096
#define Ndim 4096

typedef __attribute__((ext_vector_type(8))) short bf16x8;   // 8 bf16 (MFMA A/B frag)
typedef __attribute__((ext_vector_type(4))) float f32x4;    // 16x16 MFMA C/D frag

static __device__ __forceinline__ unsigned short f2bf_rne(float f) {
    union { float f; unsigned u; } v; v.f = f;
    unsigned u = v.u;
    u += 0x7FFFu + ((u >> 16) & 1u);
    return (unsigned short)(u >> 16);
}

static __device__ __forceinline__ void gload_lds16(const unsigned short* g, unsigned short* l) {
    __builtin_amdgcn_global_load_lds(
        (const __attribute__((address_space(1))) unsigned int*)g,
        (__attribute__((address_space(3))) unsigned int*)l,
        16, 0, 0);
}

#define BAR()   do { asm volatile("" ::: "memory"); __builtin_amdgcn_s_barrier(); asm volatile("" ::: "memory"); } while (0)
#define VMC(N)  asm volatile("s_waitcnt vmcnt(" #N ")" ::: "memory")
#define SB()    __builtin_amdgcn_sched_barrier(0)

// ---------------------------------------------------------------------------
// Packing kernels: f32 -> bf16, k-major 16B-unit layout (unchanged).
// A_p[(kt*8+o)*4096 + row] = A[row][kt*64+o*8 .. +8]
// B_p[(kt*8+o)*4096 + col] = B[kt*64+o*8 .. +8][col]   (B^T, k-major)
// ---------------------------------------------------------------------------
__global__ void conv_a_pack(const float* __restrict__ a, unsigned short* __restrict__ out) {
    __shared__ float tile[64][65];
    const int kt = blockIdx.x, rt = blockIdx.y;
    for (int i = threadIdx.x; i < 64 * 64; i += 256) {
        int r = i >> 6, c = i & 63;
        tile[r][c] = a[(size_t)(rt * 64 + r) * Kdim + kt * 64 + c];
    }
    __syncthreads();
    for (int i = threadIdx.x; i < 512; i += 256) {
        int o = i >> 6, r = i & 63;
        bf16x8 v;
#pragma unroll
        for (int e = 0; e < 8; ++e) v[e] = (short)f2bf_rne(tile[r][o * 8 + e]);
        ((bf16x8*)out)[(size_t)(kt * 8 + o) * 4096 + rt * 64 + r] = v;
    }
}

__global__ void conv_b_pack(const float* __restrict__ b, unsigned short* __restrict__ out) {
    __shared__ float tile[64][65];
    const int kt = blockIdx.x, nt = blockIdx.y;
    for (int i = threadIdx.x; i < 64 * 64; i += 256) {
        int kk = i >> 6, n = i & 63;
        tile[kk][n] = b[(size_t)(kt * 64 + kk) * Ndim + nt * 64 + n];
    }
    __syncthreads();
    for (int i = threadIdx.x; i < 512; i += 256) {
        int o = i >> 6, n = i & 63;
        bf16x8 v;
#pragma unroll
        for (int e = 0; e < 8; ++e) v[e] = (short)f2bf_rne(tile[o * 8 + e][n]);
        ((bf16x8*)out)[(size_t)(kt * 8 + o) * 4096 + nt * 64 + n] = v;
    }
}

// ---------------------------------------------------------------------------
// 128x128 bf16 GEMM, 16x16x32 MFMA, BK=32, 32 KiB LDS -> 3 blocks/CU
// (12 waves/CU, reg-limited at ~152 regs/wave) -- first true occupancy
// increase: co-resident blocks' MFMA waves cover each block's VMC(0) stall
// and read windows (m97/m114 mechanism).
// 256 thr = 4 waves (2M x 2N); per-wave 64x64 = acc[4][4] f32x4 (64 AGPR).
// LDS: buf(2) x [A 8KB | B 8KB] = 32 KiB. k-major: 4 slabs (k-octets) x
// 128 rows x 16B per region; frag ds_read_b128 = 16-lane quarter reads 256
// contiguous bytes -> conflict-free (r7-r11 verified, counter 0).
//
// Per K-tile t (buf P, other Q), 2 windows; X/Y frag sets by tile parity
// (cur = this tile's frags, read during PREVIOUS tile's w1):
//   w0: [stage 4 loads tile t+1 -> Q] SB [8 MFMA m0,m1 (cur)] SB
//   w1: VMC(0) BAR [rd 12 frags (Q) -> nxt] SB [8 MFMA m2,m3 (cur)] SB BAR
// WAR: Q's frags were read at t-1 w1, consumed by t's MFMAs; ds_reads issued
// before t-1's end-BAR, stage after it (r11-validated discipline). RAW:
// VMC(0) retires the 4 stage loads + BAR before Q reads.
// ---------------------------------------------------------------------------
__global__ __launch_bounds__(256, 3) void gemm3b(const unsigned short* __restrict__ Ap,
                                                 const unsigned short* __restrict__ Bp,
                                                 float* __restrict__ C) {
    __shared__ unsigned short lds[16384];  // 32 KiB

    const int lane = threadIdx.x & 63;
    const int w    = threadIdx.x >> 6;   // 0..3
    const int wm   = w >> 1;             // 0..1
    const int wn   = w & 1;              // 0..1

    // bijective XCD swizzle (gridDim.x = 1024, 1024 % 8 == 0)
    const int nch = gridDim.x >> 3;
    const int swz = (blockIdx.x & 7) * nch + (blockIdx.x >> 3);
    const int bm  = swz >> 5;            // 0..31
    const int bn  = swz & 31;            // 0..31

    // ---- staging: wave w handles k-octet slab w of the tile (2 loads A + 2 B) ----
    // tile T: global octet g = T*4 + w; src = packed + 8*(g*4096 + row0 + lane).
    const size_t aRow = (size_t)bm * 128 + lane;
    const size_t bRow = (size_t)bn * 128 + lane;

#define STG(Q, T) do {                                                        \
        unsigned short* dA = lds + (Q) * 8192 + w * 1024;                     \
        unsigned short* dB = dA + 4096;                                       \
        const unsigned short* sA = Ap + 8 * (((size_t)((T) * 4 + w) << 12) + aRow); \
        const unsigned short* sB = Bp + 8 * (((size_t)((T) * 4 + w) << 12) + bRow); \
        gload_lds16(sA,       dA);                                            \
        gload_lds16(sA + 512, dA + 512);                                      \
        gload_lds16(sB,       dB);                                            \
        gload_lds16(sB + 512, dB + 512);                                      \
    } while (0)

    // ---- fragment reads (bytes): buf*16384 + [A:0 | B:8192] + hi*2048
    //      + row*16 (+ frag*256) ----
    const int fr = lane & 15;
    const int hi = lane >> 4;
    const char* ldsc = (const char*)lds;
    const int adA = hi * 2048 + (wm * 64 + fr) * 16;
    const int adB = 8192 + hi * 2048 + (wn * 64 + fr) * 16;

#define RD_ALL(DA, DB, Q) do { _Pragma("unroll")                              \
        for (int m_ = 0; m_ < 4; ++m_)                                        \
            DA[m_] = *(const bf16x8*)(ldsc + (Q) * 16384 + adA + m_ * 256);   \
        _Pragma("unroll")                                                     \
        for (int n_ = 0; n_ < 4; ++n_)                                        \
            DB[n_] = *(const bf16x8*)(ldsc + (Q) * 16384 + adB + n_ * 256);   \
    } while (0)

#define MFMA_HALF(H, AF, BF) do {                                             \
        __builtin_amdgcn_s_setprio(1);                                        \
        _Pragma("unroll")                                                     \
        for (int m_ = 2 * (H); m_ < 2 * (H) + 2; ++m_)                        \
            _Pragma("unroll")                                                 \
            for (int n_ = 0; n_ < 4; ++n_)                                    \
                acc[m_][n_] = __builtin_amdgcn_mfma_f32_16x16x32_bf16(        \
                    AF[m_], BF[n_], acc[m_][n_], 0, 0, 0);                    \
        __builtin_amdgcn_s_setprio(0);                                        \
    } while (0)

// One K-tile: P = this tile's buf, Q = other; CA/CB = current frags,
// NA/NB = next tile's frag set (read from Q).
#define TILE(P, Q, CA, CB, NA, NB, DO_STG, DO_NXT, DO_SYNC, T) do {           \
        if (DO_STG) STG(Q, T);                                                \
        SB();                                                                 \
        MFMA_HALF(0, CA, CB); SB();                                           \
        if (DO_SYNC) { VMC(0); BAR(); }                                       \
        if (DO_NXT) { RD_ALL(NA, NB, Q); SB(); }                              \
        MFMA_HALF(1, CA, CB); SB();                                           \
        BAR();                                                                \
    } while (0)

    f32x4 acc[4][4] = {};
    bf16x8 aX[4], bX[4], aY[4], bY[4];

    // ---- prologue: stage tile 0 -> buf0, retire, read frags -> X ----
    STG(0, 0);
    VMC(0); BAR();
    RD_ALL(aX, bX, 0);

    // ---- 128 K-tiles: loop 63 iters (tiles 0..125), epilogue 126, 127 ----
    for (int i = 0; i < 63; ++i) {
        TILE(0, 1, aX, bX, aY, bY, 1, 1, 1, 2 * i + 1);
        TILE(1, 0, aY, bY, aX, bX, 1, 1, 1, 2 * i + 2);
    }
    TILE(0, 1, aX, bX, aY, bY, 1, 1, 1, 127);   // tile 126, stages 127
    TILE(1, 0, aY, bY, aX, bX, 0, 0, 0, 0);     // tile 127

    // ---- C write: 16x16 layout col = lane&15, row = (lane>>4)*4 + reg ----
    const size_t crow = (size_t)(bm * 128 + wm * 64 + hi * 4);
    const int    ccol = bn * 128 + wn * 64 + fr;
#pragma unroll
    for (int mi = 0; mi < 4; ++mi)
#pragma unroll
        for (int ni = 0; ni < 4; ++ni) {
            const size_t row = crow + mi * 16;
            const int    col = ccol + ni * 16;
#pragma unroll
            for (int r = 0; r < 4; ++r)
                C[(row + r) * Ndim + col] = acc[mi][ni][r];
        }

#undef STG
#undef RD_ALL
#undef MFMA_HALF
#undef TILE
}

// ---------------------------------------------------------------------------
// Fallback if workspace too small: plain f32 tiles
// ---------------------------------------------------------------------------
__global__ void gemm_f32_naive(const float* __restrict__ A, const float* __restrict__ B,
                               float* __restrict__ C) {
    __shared__ float As[32][33], Bs[32][33];
    const int tx = threadIdx.x & 31, ty = threadIdx.x >> 5;
    const int row0 = blockIdx.y * 32, col0 = blockIdx.x * 32;
    float acc[4] = {0.f, 0.f, 0.f, 0.f};
    for (int k0 = 0; k0 < Kdim; k0 += 32) {
        for (int i = threadIdx.x; i < 32 * 32; i += 256) {
            int r = i >> 5, c = i & 31;
            As[r][c] = A[(size_t)(row0 + r) * Kdim + k0 + c];
            Bs[r][c] = B[(size_t)(k0 + r) * Ndim + col0 + c];
        }
        __syncthreads();
#pragma unroll 8
        for (int kk = 0; kk < 32; ++kk) {
            float bv = Bs[kk][tx];
#pragma unroll
            for (int i = 0; i < 4; ++i) acc[i] += As[ty + 8 * i][kk] * bv;
        }
        __syncthreads();
    }
#pragma unroll
    for (int i = 0; i < 4; ++i)
        C[(size_t)(row0 + ty + 8 * i) * Ndim + col0 + tx] = acc[i];
}

extern "C" void kernel_launch(void* const* d_in, const int* in_sizes, int n_in,
                              void* d_out, int out_size, void* d_ws, size_t ws_size,
                              hipStream_t stream) {
    const float* x = (const float*)d_in[0];
    const float* y = (const float*)d_in[1];
    float* out = (float*)d_out;

    const size_t elemsA = (size_t)Mdim * Kdim;
    const size_t elemsB = (size_t)Ndim * Kdim;
    const size_t need   = (elemsA + elemsB) * sizeof(unsigned short);  // 64 MiB

    if (ws_size >= need) {
        unsigned short* Apk = (unsigned short*)d_ws;
        unsigned short* Bpk = Apk + elemsA;

        conv_a_pack<<<dim3(Kdim / 64, Mdim / 64), 256, 0, stream>>>(x, Apk);
        conv_b_pack<<<dim3(Kdim / 64, Ndim / 64), 256, 0, stream>>>(y, Bpk);
        gemm3b<<<dim3((Mdim / 128) * (Ndim / 128)), 256, 0, stream>>>(Apk, Bpk, out);
    } else {
        gemm_f32_naive<<<dim3(Ndim / 32, Mdim / 32), 256, 0, stream>>>(x, y, out);
    }
}

// Round 13
// 146.184 us; speedup vs baseline: 1.3365x; 1.3365x over previous
//
#include <hip/hip_runtime.h>
#include <stdint.h>

#define Mdim 4096
#define Kdim 4096
#define Ndim 4096

typedef __attribute__((ext_vector_type(8))) short bf16x8;   // 8 bf16 (MFMA A/B frag)
typedef __attribute__((ext_vector_type(4))) float f32x4;    // 16x16 MFMA C/D frag

static __device__ __forceinline__ unsigned short f2bf_rne(float f) {
    union { float f; unsigned u; } v; v.f = f;
    unsigned u = v.u;
    u += 0x7FFFu + ((u >> 16) & 1u);
    return (unsigned short)(u >> 16);
}

static __device__ __forceinline__ void gload_lds16(const unsigned short* g, unsigned short* l) {
    __builtin_amdgcn_global_load_lds(
        (const __attribute__((address_space(1))) unsigned int*)g,
        (__attribute__((address_space(3))) unsigned int*)l,
        16, 0, 0);
}

#define BAR()  do { asm volatile("" ::: "memory"); __builtin_amdgcn_s_barrier(); asm volatile("" ::: "memory"); } while (0)
#define VMC(N) asm volatile("s_waitcnt vmcnt(" #N ")" ::: "memory")
#define SB()   __builtin_amdgcn_sched_barrier(0)

// ---------------------------------------------------------------------------
// Conversion kernels: f32 -> bf16 (A linear, B transposed so GEMM sees B^T)
// ---------------------------------------------------------------------------
__global__ void conv_a(const float* __restrict__ a, unsigned short* __restrict__ out) {
    size_t idx = (size_t)blockIdx.x * blockDim.x + threadIdx.x;
    float4 v = ((const float4*)a)[idx];
    ushort4 o;
    o.x = f2bf_rne(v.x); o.y = f2bf_rne(v.y); o.z = f2bf_rne(v.z); o.w = f2bf_rne(v.w);
    ((ushort4*)out)[idx] = o;
}

__global__ void conv_bt(const float* __restrict__ b, unsigned short* __restrict__ bt) {
    __shared__ float tile[64][65];
    const int tn = blockIdx.x, tk = blockIdx.y;
    for (int i = threadIdx.x; i < 64 * 64; i += 256) {
        int r = i >> 6, c = i & 63;
        tile[r][c] = b[(size_t)(tk * 64 + r) * Ndim + tn * 64 + c];
    }
    __syncthreads();
    for (int i = threadIdx.x; i < 64 * 64; i += 256) {
        int n = i >> 6, k = i & 63;
        bt[(size_t)(tn * 64 + n) * Kdim + tk * 64 + k] = f2bf_rne(tile[k][n]);
    }
}

// ---------------------------------------------------------------------------
// 256x256 bf16 GEMM (C = A*B, B as B^T), 16x16x32 MFMA, 4 register-pipelined
// windows per K-tile, 2 barriers per tile. Round-6 kernel (session-best gemm,
// 116.4 us, MfmaUtil 48-51, SQ_LDS_BANK_CONFLICT = 0) with ONE change:
// s_setprio removed from MFMA blocks (T5 is null-to-negative on lockstep
// barrier-synced GEMM structures -- m190: -14 TF; all waves here are
// barrier-locked, so the prio toggle is pure overhead).
//
// 512 thr = 8 waves (2M x 4N); per-wave 128x64 out = acc[8][4] f32x4.
// BK=64 -> kk in {0,1}. LDS: buf(2) x [A 32KB | B 32KB] = 128 KiB.
// Swizzle: stored 16B-chunk c of row r holds logical chunk c^(r&7); applied
// by pre-swizzling the gload SOURCE; fragment reads XOR the chunk with fr&7.
// 16-lane row groups x 4 hi k-chunks => 2 lanes/chunk = conflict-free.
//
// Per K-tile t (buf P, other Q):
//  w0: [stage 8 loads t+1->Q] [rdA(P,kk0,mh1)->aO]     [16 MFMA mh0,kk0(aE,bE)] SB
//  w1: [rdA(P,kk1,mh0)->aE; rdB(P,kk1)->bO]            [16 MFMA mh1,kk0(aO,bE)] SB
//  w2: [rdA(P,kk1,mh1)->aO]                            [16 MFMA mh0,kk1(aE,bO)] SB
//  w3: VMC(0) BAR [rdA(Q,kk0,mh0)->aE; rdB(Q,kk0)->bE] [16 MFMA mh1,kk1(aO,bO)] SB BAR
// Every MFMA consumes only prior-window reads (compiler-counted lgkmcnt ->
// LDS drain overlaps MFMA). VMC(0) at w3 retires the 8 stage loads issued at
// w0 (~3 windows > HBM latency). WAR: all reads of buf Q complete by tile
// t-1's w3-MFMA lgkm wait (in-order DS), before the end-BAR preceding the
// stage into Q. sched_barrier(0) pins windows against compiler sinking.
// ---------------------------------------------------------------------------
__global__ __launch_bounds__(512, 2) void gemm16w(const unsigned short* __restrict__ A,
                                                  const unsigned short* __restrict__ Bt,
                                                  float* __restrict__ C) {
    __shared__ unsigned short lds[65536];  // 128 KiB

    const int lane = threadIdx.x & 63;
    const int w    = threadIdx.x >> 6;   // 0..7
    const int wm   = w >> 2;             // 0..1
    const int wn   = w & 3;              // 0..3

    // bijective XCD swizzle (gridDim.x = 256)
    const int nch = gridDim.x >> 3;
    const int swz = (blockIdx.x & 7) * nch + (blockIdx.x >> 3);
    const int bm  = swz >> 4;
    const int bn  = swz & 15;

    // ---- staging: instr j covers rows 64j + 8w + (lane>>3), pre-swizzled chunk ----
    const int schk = ((lane & 7) ^ (lane >> 3)) * 8;   // source elems
    const int srow = 8 * w + (lane >> 3);
    const unsigned short* gA0 = A  + ((size_t)(bm * 256 +   0 + srow) << 12) + schk;
    const unsigned short* gA1 = A  + ((size_t)(bm * 256 +  64 + srow) << 12) + schk;
    const unsigned short* gA2 = A  + ((size_t)(bm * 256 + 128 + srow) << 12) + schk;
    const unsigned short* gA3 = A  + ((size_t)(bm * 256 + 192 + srow) << 12) + schk;
    const unsigned short* gB0 = Bt + ((size_t)(bn * 256 +   0 + srow) << 12) + schk;
    const unsigned short* gB1 = Bt + ((size_t)(bn * 256 +  64 + srow) << 12) + schk;
    const unsigned short* gB2 = Bt + ((size_t)(bn * 256 + 128 + srow) << 12) + schk;
    const unsigned short* gB3 = Bt + ((size_t)(bn * 256 + 192 + srow) << 12) + schk;

#define STAGE_ALL(Q) do {                                                   \
        unsigned short* d = lds + (Q) * 32768 + w * 512;                    \
        gload_lds16(gA0, d);            gload_lds16(gA1, d + 4096);         \
        gload_lds16(gA2, d + 8192);     gload_lds16(gA3, d + 12288);        \
        gload_lds16(gB0, d + 16384);    gload_lds16(gB1, d + 20480);        \
        gload_lds16(gB2, d + 24576);    gload_lds16(gB3, d + 28672);        \
    } while (0)
#define ADV() do { gA0 += 64; gA1 += 64; gA2 += 64; gA3 += 64;              \
                   gB0 += 64; gB1 += 64; gB2 += 64; gB3 += 64; } while (0)

    // ---- fragment read addressing (round-2 conflict-free pattern) ----
    const int fr = lane & 15;
    const int hi = lane >> 4;
    const int sx = fr & 7;
    const char* ldsc = (const char*)lds;

    const int ckE = ((0 * 4 + hi) ^ sx) << 4;   // kk0 swizzled chunk (bytes)
    const int ckO = ((1 * 4 + hi) ^ sx) << 4;   // kk1

    const int adA0 = 0 * 65536 +         (wm * 128 + fr) * 128;
    const int adA1 = 1 * 65536 +         (wm * 128 + fr) * 128;
    const int adB0 = 0 * 65536 + 32768 + (wn *  64 + fr) * 128;
    const int adB1 = 1 * 65536 + 32768 + (wn *  64 + fr) * 128;

#define RD_A(DST, BUF, CK, MH) do { _Pragma("unroll")                        \
        for (int m_ = 0; m_ < 4; ++m_)                                       \
            DST[m_] = *(const bf16x8*)(ldsc + adA##BUF + (CK) +              \
                                       (MH) * 8192 + m_ * 2048);             \
    } while (0)
#define RD_B(DST, BUF, CK) do { _Pragma("unroll")                            \
        for (int n_ = 0; n_ < 4; ++n_)                                       \
            DST[n_] = *(const bf16x8*)(ldsc + adB##BUF + (CK) + n_ * 2048);  \
    } while (0)

#define MFMA_H(MH, AF, BF) do {                                              \
        _Pragma("unroll")                                                    \
        for (int m_ = 0; m_ < 4; ++m_)                                       \
            _Pragma("unroll")                                                \
            for (int n_ = 0; n_ < 4; ++n_)                                   \
                acc[(MH) * 4 + m_][n_] = __builtin_amdgcn_mfma_f32_16x16x32_bf16( \
                    AF[m_], BF[n_], acc[(MH) * 4 + m_][n_], 0, 0, 0);        \
    } while (0)

// One K-tile: P = this tile's buf (0/1 literal), Q = other buf.
#define TILE(P, Q, DO_STG, DO_NXT, DO_SYNC) do {                             \
        if (DO_STG) STAGE_ALL(Q);                                            \
        RD_A(aO, P, ckE, 1);                                                 \
        MFMA_H(0, aE, bE); SB();                                             \
        RD_A(aE, P, ckO, 0); RD_B(bO, P, ckO);                               \
        MFMA_H(1, aO, bE); SB();                                             \
        RD_A(aO, P, ckO, 1);                                                 \
        MFMA_H(0, aE, bO); SB();                                             \
        if (DO_SYNC) { VMC(0); BAR(); }                                      \
        if (DO_NXT) { RD_A(aE, Q, ckE, 0); RD_B(bE, Q, ckE); }               \
        MFMA_H(1, aO, bO); SB();                                             \
        BAR();                                                               \
        if (DO_STG) ADV();                                                   \
    } while (0)

    f32x4 acc[8][4] = {};
    bf16x8 aE[4], aO[4], bE[4], bO[4];

    // ---- prologue: stage tile 0 -> buf0, retire, read kk0/mh0 frags ----
    STAGE_ALL(0); ADV();
    VMC(0); BAR();
    RD_A(aE, 0, ckE, 0); RD_B(bE, 0, ckE);

    // ---- tiles 0..61 (each stages t+1), tile 62 (stages 63), tile 63 ----
    for (int i = 0; i < 31; ++i) {
        TILE(0, 1, 1, 1, 1);
        TILE(1, 0, 1, 1, 1);
    }
    TILE(0, 1, 1, 1, 1);   // tile 62
    TILE(1, 0, 0, 0, 0);   // tile 63

    // ---- C write: 16x16 layout col = lane&15, row = (lane>>4)*4 + reg ----
    const size_t crow = (size_t)(bm * 256 + wm * 128 + hi * 4);
    const int    ccol = bn * 256 + wn * 64 + fr;
#pragma unroll
    for (int mi = 0; mi < 8; ++mi)
#pragma unroll
        for (int ni = 0; ni < 4; ++ni) {
            const size_t row = crow + mi * 16;
            const int    col = ccol + ni * 16;
#pragma unroll
            for (int r = 0; r < 4; ++r)
                C[(row + r) * Ndim + col] = acc[mi][ni][r];
        }

#undef STAGE_ALL
#undef ADV
#undef RD_A
#undef RD_B
#undef MFMA_H
#undef TILE
}

// ---------------------------------------------------------------------------
// Fallback if workspace too small: plain f32 tiles
// ---------------------------------------------------------------------------
__global__ void gemm_f32_naive(const float* __restrict__ A, const float* __restrict__ B,
                               float* __restrict__ C) {
    __shared__ float As[32][33], Bs[32][33];
    const int tx = threadIdx.x & 31, ty = threadIdx.x >> 5;
    const int row0 = blockIdx.y * 32, col0 = blockIdx.x * 32;
    float acc[4] = {0.f, 0.f, 0.f, 0.f};
    for (int k0 = 0; k0 < Kdim; k0 += 32) {
        for (int i = threadIdx.x; i < 32 * 32; i += 256) {
            int r = i >> 5, c = i & 31;
            As[r][c] = A[(size_t)(row0 + r) * Kdim + k0 + c];
            Bs[r][c] = B[(size_t)(k0 + r) * Ndim + col0 + c];
        }
        __syncthreads();
#pragma unroll 8
        for (int kk = 0; kk < 32; ++kk) {
            float bv = Bs[kk][tx];
#pragma unroll
            for (int i = 0; i < 4; ++i) acc[i] += As[ty + 8 * i][kk] * bv;
        }
        __syncthreads();
    }
#pragma unroll
    for (int i = 0; i < 4; ++i)
        C[(size_t)(row0 + ty + 8 * i) * Ndim + col0 + tx] = acc[i];
}

extern "C" void kernel_launch(void* const* d_in, const int* in_sizes, int n_in,
                              void* d_out, int out_size, void* d_ws, size_t ws_size,
                              hipStream_t stream) {
    const float* x = (const float*)d_in[0];
    const float* y = (const float*)d_in[1];
    float* out = (float*)d_out;

    const size_t elemsA = (size_t)Mdim * Kdim;
    const size_t elemsB = (size_t)Ndim * Kdim;
    const size_t need   = (elemsA + elemsB) * sizeof(unsigned short);  // 64 MiB

    if (ws_size >= need) {
        unsigned short* Abf = (unsigned short*)d_ws;
        unsigned short* Btb = Abf + elemsA;

        conv_a<<<(unsigned)(elemsA / 4 / 256), 256, 0, stream>>>(x, Abf);
        conv_bt<<<dim3(Ndim / 64, Kdim / 64), 256, 0, stream>>>(y, Btb);
        gemm16w<<<dim3((Mdim / 256) * (Ndim / 256)), 512, 0, stream>>>(Abf, Btb, out);
    } else {
        gemm_f32_naive<<<dim3(Ndim / 32, Mdim / 32), 256, 0, stream>>>(x, y, out);
    }
}